// Round 8
// baseline (204.207 us; speedup 1.0000x reference)
//
#include <hip/hip_runtime.h>
#include <stdint.h>

// ---------------- problem constants ----------------
#define BB 4
#define RR 4
#define NN 4096
#define MM 64
#define KK 3
#define KNN 12288           // KK*NN
#define BRR 16              // BB*RR
#define FF 512

// canonical bf16 weight arena offsets (elements)
#define W_FPW1 0
#define W_FPW2 4096
#define W_FPW3 12288
#define W_GPW0 28928
#define W_GPW1 62208
#define W_GPW2 127744
#define W_GPW3 258816
#define W_FPB1 587520
#define W_FPB2 587584
#define W_FPB3 587712
#define W_GPB0 587840
#define W_GPB1 588096
#define W_GPB2 588352
#define W_GPB3 588864
#define W_FPB0 589376
#define W_FPW0 589440
#define W_TOT  589568

typedef short bf16x8 __attribute__((ext_vector_type(8)));
typedef float f32x4 __attribute__((ext_vector_type(4)));

__device__ __forceinline__ float bf2f(unsigned int u) {
  union { unsigned int i; float f; } v; v.i = u << 16; return v.f;
}
__device__ __forceinline__ unsigned short f2bf(float f) {
  union { float f; unsigned int i; } v; v.f = f;
  unsigned int x = v.i;
  return (unsigned short)((x + 0x7fffu + ((x >> 16) & 1u)) >> 16);
}
__device__ __forceinline__ unsigned int f2bf2(float a, float b) {
#if __has_builtin(__builtin_amdgcn_cvt_pk_bf16_f32)
  typedef __bf16 bf2_t __attribute__((ext_vector_type(2)));
  union { bf2_t v; unsigned int u; } c;
  c.v = __builtin_amdgcn_cvt_pk_bf16_f32(a, b);
  return c.u;
#else
  return (unsigned int)f2bf(a) | ((unsigned int)f2bf(b) << 16);
#endif
}
__device__ __forceinline__ float ldf(const void* p, long i, int isbf) {
  if (isbf) return bf2f(((const unsigned short*)p)[i]);
  return ((const float*)p)[i];
}
// per-wave dtype probe: sample 64 even-index ushorts of x, vote on exponents
__device__ __forceinline__ int detect_bf(const unsigned short* xs) {
  int lane = threadIdx.x & 63;
  unsigned short u = xs[lane * 2];
  int e = (u >> 7) & 0xFF;
  int bad = (e >= 0x90 || (e > 0 && e <= 0x50)) ? 1 : 0;
  unsigned long long m = __ballot(bad);
  return __popcll(m) < 16;
}

// ---------------- K1: weight canonicalize + pooled zero (blocks >=64) + assign ------
struct SrcPtrs { const void* p[16]; };
__global__ __launch_bounds__(256) void k_pre(
    SrcPtrs sp, const void* __restrict__ x, const void* __restrict__ node,
    int* __restrict__ idx, float* __restrict__ csum, int* __restrict__ blkcnt,
    unsigned short* __restrict__ Wb, unsigned long long* __restrict__ pooled64) {
  int isbf = detect_bf((const unsigned short*)x);
  int tid = threadIdx.x;
  if (blockIdx.x >= 64) {
    int zb = blockIdx.x - 64;
    if (zb < 256) pooled64[zb * 256 + tid] = 0ull;   // zero pooled (64K u64 total)
    int t2 = zb * 256 + tid;   // pair index
    int t = t2 * 2;
    if (t >= W_TOT) return;
    int s, base;
    if (t < 28928) {
      if (t < 4096)        { s=0;  base=0; }
      else if (t < 12288)  { s=1;  base=4096; }
      else                 { s=2;  base=12288; }
    } else if (t < 587520) {
      if (t < 62208)       { s=3;  base=28928; }
      else if (t < 127744) { s=4;  base=62208; }
      else if (t < 258816) { s=5;  base=127744; }
      else                 { s=6;  base=258816; }
    } else if (t < 588864) {
      if (t < 587584)      { s=7;  base=587520; }
      else if (t < 587712) { s=8;  base=587584; }
      else if (t < 587840) { s=9;  base=587712; }
      else if (t < 588096) { s=10; base=587840; }
      else if (t < 588352) { s=11; base=588096; }
      else                 { s=12; base=588352; }
    } else {
      if (t < 589376)      { s=13; base=588864; }
      else if (t < 589440) { s=14; base=589376; }
      else                 { s=15; base=589440; }
    }
    int local = t - base;                      // even (all bases even)
    unsigned int pk;
    if (isbf) pk = *(const unsigned int*)((const unsigned short*)sp.p[s] + local);
    else {
      const float* fp = (const float*)sp.p[s] + local;
      pk = f2bf2(fp[0], fp[1]);
    }
    *(unsigned int*)(Wb + t) = pk;
    return;
  }
  // ---- assign part ----
  __shared__ float nd[2][64];
  __shared__ float cs[192];
  int b = blockIdx.x >> 4;
  int n = ((blockIdx.x & 15) << 8) + tid;
  if (tid < 128) nd[tid >> 6][tid & 63] = ldf(node, b * 128 + tid, isbf);
  if (tid < 192) cs[tid] = 0.f;
  __syncthreads();
  float x0 = ldf(x, b * 8192 + n, isbf);
  float x1 = ldf(x, b * 8192 + 4096 + n, isbf);
  float d0 = 1e30f, d1 = 1e30f, d2 = 1e30f;
  int m0 = 0, m1 = 0, m2 = 0;
#pragma unroll 8
  for (int m = 0; m < 64; ++m) {
    float dx = x0 - nd[0][m];
    float dy = x1 - nd[1][m];
    float d = __fmul_rn(dx, dx) + __fmul_rn(dy, dy);
    if (d < d0)      { d2=d1; m2=m1; d1=d0; m1=m0; d0=d; m0=m; }
    else if (d < d1) { d2=d1; m2=m1; d1=d;  m1=m; }
    else if (d < d2) { d2=d;  m2=m; }
  }
  long base = ((long)b * NN + n) * 3;
  idx[base] = m0; idx[base + 1] = m1; idx[base + 2] = m2;
  atomicAdd(&cs[m0*3+0], x0); atomicAdd(&cs[m0*3+1], x1); atomicAdd(&cs[m0*3+2], 1.f);
  atomicAdd(&cs[m1*3+0], x0); atomicAdd(&cs[m1*3+1], x1); atomicAdd(&cs[m1*3+2], 1.f);
  atomicAdd(&cs[m2*3+0], x0); atomicAdd(&cs[m2*3+1], x1); atomicAdd(&cs[m2*3+2], 1.f);
  __syncthreads();
  if (tid < 192) atomicAdd(&csum[b * 192 + tid], cs[tid]);
  if (tid < 64) blkcnt[blockIdx.x * 64 + tid] = (int)cs[tid*3 + 2];
}

// ---------------- K2: means + prefix + counting-sort scatter ------------------------
__global__ __launch_bounds__(256) void k_mid(
    const float* __restrict__ csum, const int* __restrict__ blkcnt,
    const int* __restrict__ idx,
    float* __restrict__ noderot, int* __restrict__ rowflag,
    int* __restrict__ sorted) {
  __shared__ float cls[192];
  __shared__ int offs[64];
  __shared__ int lbase[64];
  __shared__ int lc[64];
  int tid = threadIdx.x;
  int blk = blockIdx.x;           // b*16 + chunk
  int b = blk >> 4, chunk = blk & 15;
  if (tid < 192) cls[tid] = csum[b * 192 + tid];
  __syncthreads();
  if (tid < 64) {
    int m = tid;
    float s0 = cls[m*3], s1 = cls[m*3+1], c = cls[m*3+2];
    float mx = s0 / (c + 1e-5f), my = s1 / (c + 1e-5f);
    rowflag[b*64 + m] = (c > 0.f) ? 1 : 0;
    for (int r = 0; r < 4; ++r) {
      float th = 1.5707964f * (float)r;
      float cr = cosf(th), sr = sinf(th);
      noderot[((b*4+r)*2+0)*64 + m] = cr*mx - sr*my;
      noderot[((b*4+r)*2+1)*64 + m] = sr*mx + cr*my;
    }
    lc[m] = 0;
  }
  if (tid == 0) {
    int acc = 0;
    for (int mm = 0; mm < 64; ++mm) { offs[mm] = acc; acc += (int)cls[mm*3+2]; }
  }
  __syncthreads();
  if (tid < 64) {
    int base = offs[tid];
    for (int c2 = 0; c2 < chunk; ++c2) base += blkcnt[(b*16 + c2)*64 + tid];
    lbase[tid] = base;
  }
  __syncthreads();
  int n = (chunk << 8) + tid;
#pragma unroll
  for (int kk = 0; kk < 3; ++kk) {
    int m = idx[((long)b*NN + n)*3 + kk];
    int pos = atomicAdd(&lc[m], 1);
    sorted[b*KNN + lbase[m] + pos] = (m << 12) | n;
  }
}

// ---------------- K3: fused fp block, 512 thr / 128 cols per block -------------------
// grid (96, 16). LDS = 52 KB exactly -> 3 blocks/CU (24 waves/CU).
// mcol lives in Cs[col*136 + 130] (padding slot; data occupies 0..129).
__global__ __launch_bounds__(512, 6) void k_fused(
    const void* __restrict__ x, const int* __restrict__ sorted,
    const int* __restrict__ idx, const float* __restrict__ noderot,
    const unsigned short* __restrict__ Wb,
    unsigned int* __restrict__ pooled, float* __restrict__ feat0) {
  __shared__ unsigned short Cs[128 * 136];  // [col][0..1]=xdec,[2..129]=h2;[130]=m|flag; later [0..127]=feat
  __shared__ unsigned short Hs[128 * 72];   // h1 (stride 72 -> 144B)
  const unsigned short* fW1 = Wb + W_FPW1;
  const unsigned short* fW2 = Wb + W_FPW2;
  const unsigned short* fW3 = Wb + W_FPW3;
  const unsigned short* fb1 = Wb + W_FPB1;
  const unsigned short* fb2 = Wb + W_FPB2;
  const unsigned short* fb3 = Wb + W_FPB3;
  const unsigned short* fb0 = Wb + W_FPB0;
  const unsigned short* fW0 = Wb + W_FPW0;
  int isbf = detect_bf((const unsigned short*)x);
  int tid = threadIdx.x, lane = tid & 63, wv = tid >> 6;   // wv 0..7
  int quad = lane >> 4, lr = lane & 15;
  int br = blockIdx.y, b = br >> 2, r = br & 3;
  if (tid < 128) {
    int e = sorted[b * KNN + blockIdx.x * 128 + tid];
    int m = e >> 12, n = e & 4095;
    int isz = (n == 0 && m == idx[(long)b * NN * 3]) ? 256 : 0;
    Cs[tid * 136 + 130] = (unsigned short)(m | isz);
    float x0 = ldf(x, b*8192 + n, isbf), x1 = ldf(x, b*8192 + 4096 + n, isbf);
    float th = 1.5707964f * (float)r;
    float cr = cosf(th), sr = sinf(th);
    float xd0 = (cr*x0 - sr*x1) - noderot[(br*2 + 0)*64 + m];
    float xd1 = (sr*x0 + cr*x1) - noderot[(br*2 + 1)*64 + m];
    *(unsigned int*)&Cs[tid * 136] = f2bf2(xd0, xd1);
  }
  __syncthreads();
  // ----- layer0 (2 -> 64), VALU: col=tid&127, rows og..og+15 -----
  {
    int col = tid & 127, og = (tid >> 7) << 4;   // 0,16,32,48
    unsigned int xu = *(unsigned int*)&Cs[col * 136];
    float fx0 = bf2f(xu & 0xffff), fx1 = bf2f(xu >> 16);
    union { unsigned int u[8]; bf16x8 v[2]; } o8;
#pragma unroll
    for (int j = 0; j < 16; j += 2) {
      int o = og + j;
      unsigned int wu0 = *(const unsigned int*)&fW0[o*2];
      unsigned int wu1 = *(const unsigned int*)&fW0[o*2 + 2];
      float h0 = bf2f(fb0[o])   + bf2f(wu0 & 0xffff)*fx0 + bf2f(wu0 >> 16)*fx1;
      float h1 = bf2f(fb0[o+1]) + bf2f(wu1 & 0xffff)*fx0 + bf2f(wu1 >> 16)*fx1;
      o8.u[j >> 1] = f2bf2(fmaxf(h0, 0.f), fmaxf(h1, 0.f));
    }
    *(bf16x8*)&Hs[col*72 + og]     = o8.v[0];
    *(bf16x8*)&Hs[col*72 + og + 8] = o8.v[1];
  }
  __syncthreads();
  // ----- layer1 (64 -> 64): wave = rows (wv&3)*16 x cols (wv>>2)*64 -----
  {
    int o0 = (wv & 3) * 16, cb = (wv >> 2) * 64;
    f32x4 acc[4];
    float bb4[4];
#pragma unroll
    for (int rr = 0; rr < 4; ++rr) bb4[rr] = bf2f(fb1[o0 + quad*4 + rr]);
#pragma unroll
    for (int nt = 0; nt < 4; ++nt) acc[nt] = (f32x4){bb4[0], bb4[1], bb4[2], bb4[3]};
#pragma unroll
    for (int ks = 0; ks < 64; ks += 32) {
      bf16x8 a = *(const bf16x8*)(fW1 + (o0 + lr)*64 + ks + quad*8);
#pragma unroll
      for (int nt = 0; nt < 4; ++nt) {
        bf16x8 bf = *(bf16x8*)&Hs[(cb + nt*16 + lr)*72 + ks + quad*8];
        acc[nt] = __builtin_amdgcn_mfma_f32_16x16x32_bf16(a, bf, acc[nt], 0, 0, 0);
      }
    }
    __syncthreads();  // all Hs reads done
#pragma unroll
    for (int nt = 0; nt < 4; ++nt) {
      int col = cb + nt*16 + lr;
      unsigned long long pk =
        (unsigned long long)f2bf2(fmaxf(acc[nt][0],0.f), fmaxf(acc[nt][1],0.f)) |
        ((unsigned long long)f2bf2(fmaxf(acc[nt][2],0.f), fmaxf(acc[nt][3],0.f)) << 32);
      *(unsigned long long*)&Hs[col*72 + o0 + quad*4] = pk;
    }
  }
  __syncthreads();
  // ----- layer2 (64 -> 128): wave = rows wv*16 x all 128 cols -----
  {
    int o0 = wv * 16;
    f32x4 acc[8];
    float bb4[4];
#pragma unroll
    for (int rr = 0; rr < 4; ++rr) bb4[rr] = bf2f(fb2[o0 + quad*4 + rr]);
#pragma unroll
    for (int nt = 0; nt < 8; ++nt) acc[nt] = (f32x4){bb4[0], bb4[1], bb4[2], bb4[3]};
#pragma unroll
    for (int ks = 0; ks < 64; ks += 32) {
      bf16x8 a = *(const bf16x8*)(fW2 + (o0 + lr)*64 + ks + quad*8);
#pragma unroll
      for (int nt = 0; nt < 8; ++nt) {
        bf16x8 bf = *(bf16x8*)&Hs[(nt*16 + lr)*72 + ks + quad*8];
        acc[nt] = __builtin_amdgcn_mfma_f32_16x16x32_bf16(a, bf, acc[nt], 0, 0, 0);
      }
    }
#pragma unroll
    for (int nt = 0; nt < 8; ++nt) {  // write into Cs[2..129] (disjoint from Hs, slot130)
      int col = nt*16 + lr;
      int o = o0 + quad*4;
      *(unsigned int*)&Cs[col*136 + 2 + o] = f2bf2(fmaxf(acc[nt][0],0.f), fmaxf(acc[nt][1],0.f));
      *(unsigned int*)&Cs[col*136 + 4 + o] = f2bf2(fmaxf(acc[nt][2],0.f), fmaxf(acc[nt][3],0.f));
    }
  }
  __syncthreads();
  // ----- layer3 (130 -> 128): wave = rows wv*16 x all 128 cols -----
  f32x4 acc3[8];
  {
    int o0 = wv * 16;
    float bb4[4];
#pragma unroll
    for (int rr = 0; rr < 4; ++rr) bb4[rr] = bf2f(fb3[o0 + quad*4 + rr]);
#pragma unroll
    for (int nt = 0; nt < 8; ++nt) acc3[nt] = (f32x4){bb4[0], bb4[1], bb4[2], bb4[3]};
#pragma unroll
    for (int ks = 0; ks < 128; ks += 32) {
      union { bf16x8 v; unsigned int u[4]; } au;
      const unsigned int* ap = (const unsigned int*)(fW3 + (long)(o0 + lr)*130 + ks + quad*8);
      au.u[0] = ap[0]; au.u[1] = ap[1]; au.u[2] = ap[2]; au.u[3] = ap[3];
#pragma unroll
      for (int nt = 0; nt < 8; ++nt) {
        bf16x8 bf = *(bf16x8*)&Cs[(nt*16 + lr)*136 + ks + quad*8];
        acc3[nt] = __builtin_amdgcn_mfma_f32_16x16x32_bf16(au.v, bf, acc3[nt], 0, 0, 0);
      }
    }
    // K tail: channels 128..129 — hoist B reads/unpacks out of rr loop
    float bu0[8], bu1[8];
#pragma unroll
    for (int nt = 0; nt < 8; ++nt) {
      unsigned int bu = *(unsigned int*)&Cs[(nt*16 + lr)*136 + 128];
      bu0[nt] = bf2f(bu & 0xffff); bu1[nt] = bf2f(bu >> 16);
    }
#pragma unroll
    for (int rr = 0; rr < 4; ++rr) {
      int o = o0 + quad*4 + rr;
      unsigned int wu = *(const unsigned int*)(fW3 + (long)o*130 + 128);
      float w0 = bf2f(wu & 0xffff), w1 = bf2f(wu >> 16);
#pragma unroll
      for (int nt = 0; nt < 8; ++nt)
        acc3[nt][rr] += w0 * bu0[nt] + w1 * bu1[nt];
    }
  }
  __syncthreads();   // ALL Cs reads complete before feat overwrite
  {
    int o0 = wv * 16;
#pragma unroll
    for (int nt = 0; nt < 8; ++nt) {
      int col = nt*16 + lr;
      unsigned long long pk =
        (unsigned long long)f2bf2(fmaxf(acc3[nt][0],0.f), fmaxf(acc3[nt][1],0.f)) |
        ((unsigned long long)f2bf2(fmaxf(acc3[nt][2],0.f), fmaxf(acc3[nt][3],0.f)) << 32);
      *(unsigned long long*)&Cs[col*136 + o0 + quad*4] = pk;
    }
  }
  __syncthreads();
  // ----- run-scan segment max: thread = (row o, chunk h of 32 cols) -----
  {
    int o = tid & 127, h = tid >> 7;   // h 0..3
    int c0 = h * 32;
    float fv[32];
    int mcl[32];
#pragma unroll
    for (int j = 0; j < 32; ++j) {
      fv[j] = bf2f(Cs[(c0 + j)*136 + o]);
      mcl[j] = Cs[(c0 + j)*136 + 130];
    }
    int curm = mcl[0] & 255;
    float v = 0.f;
#pragma unroll
    for (int j = 0; j < 32; ++j) {
      int mm = mcl[j] & 255;
      if (mm != curm) {
        atomicMax(&pooled[(((long)br*64 + curm) << 7) + o], __float_as_uint(v));
        curm = mm; v = 0.f;
      }
      v = fmaxf(v, fv[j]);
      if (mcl[j] & 256) feat0[br*128 + o] = fv[j];
    }
    atomicMax(&pooled[(((long)br*64 + curm) << 7) + o], __float_as_uint(v));
  }
}

// ---------------- K4: finalize -> AG[1024][648] cols 0..129 -------------------------
__global__ __launch_bounds__(256) void k_fin(
    const unsigned int* __restrict__ pooled, const float* __restrict__ feat0,
    const int* __restrict__ rowflag, const float* __restrict__ noderot,
    unsigned short* __restrict__ AG) {
  int t = blockIdx.x * 256 + threadIdx.x;  // 131072
  int col = t >> 7, o = t & 127;
  int br = col >> 6, m = col & 63, b = br >> 2;
  float v = __uint_as_float(pooled[((long)col << 7) + o]);
  if (!rowflag[b*64 + m]) v = feat0[br*128 + o];
  AG[(long)col*648 + 2 + o] = f2bf(v);
  if (o < 2) AG[(long)col*648 + o] = f2bf(noderot[(br*2 + o)*64 + m]);
}

// ---------------- gp GEMM: grid (64 col-tiles, row-blocks of 64) --------------------
template<int KW, int KMAIN, bool REM2, int BSTR, int OSTR, int OOFF, int EPI, bool AAL, int TOTB>
__global__ __launch_bounds__(256) void k_gemm2(
    const unsigned short* __restrict__ W, const unsigned short* __restrict__ Bi,
    const unsigned short* __restrict__ Bb, unsigned short* __restrict__ Out,
    unsigned int* __restrict__ outmax, unsigned int* __restrict__ counter,
    const void* __restrict__ x, void* __restrict__ out) {
  __shared__ int done_s;
  int lane = threadIdx.x & 63, wv = threadIdx.x >> 6;
  int quad = lane >> 4, lr = lane & 15;
  int o0 = blockIdx.y * 64 + wv * 16;
  int p0 = blockIdx.x * 16;
  f32x4 acc;
  {
    int ob = o0 + quad*4;
    acc = (f32x4){bf2f(Bi[ob]), bf2f(Bi[ob+1]), bf2f(Bi[ob+2]), bf2f(Bi[ob+3])};
  }
  const unsigned short* arow = W + (long)(o0 + lr) * KW;
  const unsigned short* brow = Bb + (long)(p0 + lr) * BSTR;
#pragma unroll 4
  for (int ks = 0; ks < KMAIN; ks += 32) {
    bf16x8 a;
    if constexpr (AAL) {
      a = *(const bf16x8*)(arow + ks + quad*8);
    } else {
      union { bf16x8 v; unsigned int u[4]; } au;
      const unsigned int* ap = (const unsigned int*)(arow + ks + quad*8);
      au.u[0] = ap[0]; au.u[1] = ap[1]; au.u[2] = ap[2]; au.u[3] = ap[3];
      a = au.v;
    }
    bf16x8 bf = *(const bf16x8*)(brow + ks + quad*8);
    acc = __builtin_amdgcn_mfma_f32_16x16x32_bf16(a, bf, acc, 0, 0, 0);
  }
  if constexpr (REM2) {
    unsigned int bu = *(const unsigned int*)(brow + KMAIN);
    float b0v = bf2f(bu & 0xffff), b1v = bf2f(bu >> 16);
#pragma unroll
    for (int rr = 0; rr < 4; ++rr) {
      int o = o0 + quad*4 + rr;
      unsigned int wu = *(const unsigned int*)(W + (long)o * KW + KMAIN);
      acc[rr] += bf2f(wu & 0xffff) * b0v + bf2f(wu >> 16) * b1v;
    }
  }
  if constexpr (EPI == 0) {
    unsigned short* op = Out + (long)(p0 + lr) * OSTR + OOFF + o0 + quad*4;
    if constexpr (((OOFF * 2) % 8) == 0) {
      unsigned long long pk =
        (unsigned long long)f2bf2(fmaxf(acc[0],0.f), fmaxf(acc[1],0.f)) |
        ((unsigned long long)f2bf2(fmaxf(acc[2],0.f), fmaxf(acc[3],0.f)) << 32);
      *(unsigned long long*)op = pk;
    } else {
      *(unsigned int*)op       = f2bf2(fmaxf(acc[0],0.f), fmaxf(acc[1],0.f));
      *(unsigned int*)(op + 2) = f2bf2(fmaxf(acc[2],0.f), fmaxf(acc[3],0.f));
    }
  } else {  // EPI == 2
    int b = blockIdx.x >> 4;
#pragma unroll
    for (int rr = 0; rr < 4; ++rr) {
      float v = fmaxf(acc[rr], 0.f);
      v = fmaxf(v, __shfl_xor(v, 1, 64));
      v = fmaxf(v, __shfl_xor(v, 2, 64));
      v = fmaxf(v, __shfl_xor(v, 4, 64));
      v = fmaxf(v, __shfl_xor(v, 8, 64));
      if (lr == 0) atomicMax(&outmax[b * FF + o0 + quad*4 + rr], __float_as_uint(v));
    }
    __threadfence();
    __syncthreads();
    if (threadIdx.x == 0) done_s = (int)atomicAdd(counter, 1u);
    __syncthreads();
    if (done_s == TOTB - 1) {
      int isbf = detect_bf((const unsigned short*)x);
      for (int t = threadIdx.x; t < 2048; t += 256) {
        float v = __uint_as_float(atomicMax(&outmax[t], 0u));
        if (isbf) ((unsigned short*)out)[t] = f2bf(v);
        else      ((float*)out)[t] = v;
      }
    }
  }
}

// ---------------- host ----------------
extern "C" void kernel_launch(void* const* d_in, const int* in_sizes, int n_in,
                              void* d_out, int out_size, void* d_ws, size_t ws_size,
                              hipStream_t stream) {
  const void* x    = d_in[0];
  const void* node = d_in[2];

  char* ws = (char*)d_ws;
  float*          csum    = (float*)(ws + 0);              //   3072
  unsigned int*   outmax  = (unsigned int*)(ws + 3072);    //   8192
  unsigned int*   counter = (unsigned int*)(ws + 11264);   //    256
  // ---- end of memset region (11520 B) ----
  unsigned int*   pooled  = (unsigned int*)(ws + 11520);   // 524288 (zeroed by k_pre)
  int*            idx     = (int*)(ws + 535808);           // 196608
  int*            blkcnt  = (int*)(ws + 732416);           //  16384
  float*          noderot = (float*)(ws + 748800);         //   8192
  int*            rowflag = (int*)(ws + 756992);           //   1024
  int*            sorted  = (int*)(ws + 758016);           // 196608
  float*          feat0   = (float*)(ws + 954624);         //   8192
  unsigned short* Wb      = (unsigned short*)(ws + 962816);// 1179136 -> 2141952
  unsigned short* AG      = (unsigned short*)(ws + 2141952);  // 1327104 -> 3469056
  unsigned short* Hg1     = (unsigned short*)(ws + 3469056);  // 524288 -> 3993344
  unsigned short* Hg2     = (unsigned short*)(ws + 3993344);  // 524288 -> 4517632

  hipMemsetAsync(ws, 0, 11520, stream);

  SrcPtrs sp;
  sp.p[0]  = d_in[6];   // fpW1
  sp.p[1]  = d_in[8];   // fpW2
  sp.p[2]  = d_in[10];  // fpW3
  sp.p[3]  = d_in[12];  // gpW0
  sp.p[4]  = d_in[14];  // gpW1
  sp.p[5]  = d_in[16];  // gpW2
  sp.p[6]  = d_in[18];  // gpW3
  sp.p[7]  = d_in[7];   // fpb1
  sp.p[8]  = d_in[9];   // fpb2
  sp.p[9]  = d_in[11];  // fpb3
  sp.p[10] = d_in[13];  // gpb0
  sp.p[11] = d_in[15];  // gpb1
  sp.p[12] = d_in[17];  // gpb2
  sp.p[13] = d_in[19];  // gpb3
  sp.p[14] = d_in[5];   // fpb0
  sp.p[15] = d_in[4];   // fpW0

  k_pre<<<64 + (W_TOT/2 + 255) / 256, 256, 0, stream>>>(
      sp, x, node, idx, csum, blkcnt, Wb, (unsigned long long*)pooled);
  k_mid<<<64, 256, 0, stream>>>(csum, blkcnt, idx, noderot, rowflag, sorted);
  k_fused<<<dim3(96, 16), 512, 0, stream>>>(x, sorted, idx, noderot, Wb, pooled, feat0);
  k_fin<<<512, 256, 0, stream>>>(pooled, feat0, rowflag, noderot, AG);

  // gp layers, row-split: wave = 16x16 tile
  k_gemm2<130, 128, true, 648, 256, 0, 0, false, 0>
      <<<dim3(64, 4), 256, 0, stream>>>(Wb + W_GPW0, Wb + W_GPB0, AG, Hg1,
                                        nullptr, nullptr, x, nullptr);
  k_gemm2<256, 256, false, 256, 256, 0, 0, true, 0>
      <<<dim3(64, 4), 256, 0, stream>>>(Wb + W_GPW1, Wb + W_GPB1, Hg1, Hg2,
                                        nullptr, nullptr, x, nullptr);
  k_gemm2<256, 256, false, 256, 648, 130, 0, true, 0>
      <<<dim3(64, 8), 256, 0, stream>>>(Wb + W_GPW2, Wb + W_GPB2, Hg2, AG,
                                        nullptr, nullptr, x, nullptr);
  k_gemm2<642, 640, true, 648, 0, 0, 2, false, 512>
      <<<dim3(64, 8), 256, 0, stream>>>(Wb + W_GPW3, Wb + W_GPB3, AG, nullptr,
                                        outmax, counter, x, d_out);
}

// Round 9
// 203.822 us; speedup vs baseline: 1.0019x; 1.0019x over previous
//
#include <hip/hip_runtime.h>
#include <stdint.h>

// ---------------- problem constants ----------------
#define BB 4
#define RR 4
#define NN 4096
#define MM 64
#define KK 3
#define KNN 12288           // KK*NN
#define BRR 16              // BB*RR
#define FF 512

// fp/bias arena Wb2 offsets (elements)
#define F_W1 0
#define F_W2 4096
#define F_W3 12288
#define F_B1 28928
#define F_B2 28992
#define F_B3 29120
#define G_B0 29248
#define G_B1 29504
#define G_B2 29760
#define G_B3 30272
#define F_B0 30784
#define F_W0 30848
#define WB2_TOT 30976

// packed gp weight arena Wp offsets (elements): layout [(k/8)*R + r]*8 + j, K padded
#define P_W0 0          // 256 rows, K 130 -> 160
#define P_W1 40960      // 256 rows, K 256
#define P_W2 106496     // 512 rows, K 256
#define P_W3 237568     // 512 rows, K 642 -> 672
#define WP_TOT 581632

typedef short bf16x8 __attribute__((ext_vector_type(8)));
typedef float f32x4 __attribute__((ext_vector_type(4)));

__device__ __forceinline__ float bf2f(unsigned int u) {
  union { unsigned int i; float f; } v; v.i = u << 16; return v.f;
}
__device__ __forceinline__ unsigned short f2bf(float f) {
  union { float f; unsigned int i; } v; v.f = f;
  unsigned int x = v.i;
  return (unsigned short)((x + 0x7fffu + ((x >> 16) & 1u)) >> 16);
}
__device__ __forceinline__ unsigned int f2bf2(float a, float b) {
#if __has_builtin(__builtin_amdgcn_cvt_pk_bf16_f32)
  typedef __bf16 bf2_t __attribute__((ext_vector_type(2)));
  union { bf2_t v; unsigned int u; } c;
  c.v = __builtin_amdgcn_cvt_pk_bf16_f32(a, b);
  return c.u;
#else
  return (unsigned int)f2bf(a) | ((unsigned int)f2bf(b) << 16);
#endif
}
__device__ __forceinline__ float ldf(const void* p, long i, int isbf) {
  if (isbf) return bf2f(((const unsigned short*)p)[i]);
  return ((const float*)p)[i];
}
// per-wave dtype probe: sample 64 even-index ushorts of x, vote on exponents
__device__ __forceinline__ int detect_bf(const unsigned short* xs) {
  int lane = threadIdx.x & 63;
  unsigned short u = xs[lane * 2];
  int e = (u >> 7) & 0xFF;
  int bad = (e >= 0x90 || (e > 0 && e <= 0x50)) ? 1 : 0;
  unsigned long long m = __ballot(bad);
  return __popcll(m) < 16;
}

// ---------------- K1: assign (blocks 0..63) + weight canonicalize (blocks >=64) -----
struct SrcPtrs { const void* p[16]; };
__global__ __launch_bounds__(256) void k_pre(
    SrcPtrs sp, const void* __restrict__ x, const void* __restrict__ node,
    int* __restrict__ idx, float* __restrict__ csum, int* __restrict__ blkcnt,
    unsigned short* __restrict__ Wb2, unsigned short* __restrict__ Wp,
    unsigned long long* __restrict__ pooled64) {
  int isbf = detect_bf((const unsigned short*)x);
  int tid = threadIdx.x;
  if (blockIdx.x >= 64) {
    int zb = blockIdx.x - 64;
    if (zb < 256) pooled64[zb * 256 + tid] = 0ull;   // zero pooled (512 KB)
    if (blockIdx.x < 125) {
      // ---- Wb2 cvt: fp weights + all biases (row-major, 2 elems/thread) ----
      int t = (zb * 256 + tid) * 2;
      if (t >= WB2_TOT) return;
      int s, base;
      if (t < 12288) {
        if (t < 4096)        { s=0;  base=0; }
        else                 { s=1;  base=4096; }
      } else if (t < 28928)  { s=2;  base=12288; }
      else if (t < 29248) {
        if (t < 28992)       { s=7;  base=28928; }
        else if (t < 29120)  { s=8;  base=28992; }
        else                 { s=9;  base=29120; }
      } else if (t < 30272) {
        if (t < 29504)       { s=10; base=29248; }
        else if (t < 29760)  { s=11; base=29504; }
        else                 { s=12; base=29760; }
      } else {
        if (t < 30784)       { s=13; base=30272; }
        else if (t < 30848)  { s=14; base=30784; }
        else                 { s=15; base=30848; }
      }
      int local = t - base;
      unsigned int pk;
      if (isbf) pk = *(const unsigned int*)((const unsigned short*)sp.p[s] + local);
      else {
        const float* fp = (const float*)sp.p[s] + local;
        pk = f2bf2(fp[0], fp[1]);
      }
      *(unsigned int*)(Wb2 + t) = pk;
      return;
    }
    // ---- packed gp weight cvt: dst[(k8*R + r)*8 + j], zero beyond KW ----
    int t = ((blockIdx.x - 125) * 256 + tid) * 2;
    if (t >= WP_TOT) return;
    int base, KW, rs; const void* src;
    if (t < 40960)       { base=0;      KW=130; rs=8; src=sp.p[3]; }
    else if (t < 106496) { base=40960;  KW=256; rs=8; src=sp.p[4]; }
    else if (t < 237568) { base=106496; KW=256; rs=9; src=sp.p[5]; }
    else                 { base=237568; KW=642; rs=9; src=sp.p[6]; }
    int local = t - base;
    int blk = local >> 3, j = local & 7;
    int k8 = blk >> rs, r = blk & ((1 << rs) - 1);
    int k = k8 * 8 + j;
    unsigned int pk = 0u;
    if (k < KW) {
      long si = (long)r * KW + k;                 // even: KW even, k even
      if (isbf) pk = *(const unsigned int*)((const unsigned short*)src + si);
      else {
        const float* fp = (const float*)src + si;
        pk = f2bf2(fp[0], fp[1]);
      }
    }
    *(unsigned int*)(Wp + t) = pk;
    return;
  }
  // ---- assign part: top-3 + cluster sums + per-chunk histogram ----
  __shared__ float nd[2][64];
  __shared__ float cs[192];
  int b = blockIdx.x >> 4;
  int n = ((blockIdx.x & 15) << 8) + tid;
  if (tid < 128) nd[tid >> 6][tid & 63] = ldf(node, b * 128 + tid, isbf);
  if (tid < 192) cs[tid] = 0.f;
  __syncthreads();
  float x0 = ldf(x, b * 8192 + n, isbf);
  float x1 = ldf(x, b * 8192 + 4096 + n, isbf);
  float d0 = 1e30f, d1 = 1e30f, d2 = 1e30f;
  int m0 = 0, m1 = 0, m2 = 0;
#pragma unroll 8
  for (int m = 0; m < 64; ++m) {
    float dx = x0 - nd[0][m];
    float dy = x1 - nd[1][m];
    float d = __fmul_rn(dx, dx) + __fmul_rn(dy, dy);   // no contraction: match ref
    if (d < d0)      { d2=d1; m2=m1; d1=d0; m1=m0; d0=d; m0=m; }
    else if (d < d1) { d2=d1; m2=m1; d1=d;  m1=m; }
    else if (d < d2) { d2=d;  m2=m; }
  }
  long base = ((long)b * NN + n) * 3;
  idx[base] = m0; idx[base + 1] = m1; idx[base + 2] = m2;
  atomicAdd(&cs[m0*3+0], x0); atomicAdd(&cs[m0*3+1], x1); atomicAdd(&cs[m0*3+2], 1.f);
  atomicAdd(&cs[m1*3+0], x0); atomicAdd(&cs[m1*3+1], x1); atomicAdd(&cs[m1*3+2], 1.f);
  atomicAdd(&cs[m2*3+0], x0); atomicAdd(&cs[m2*3+1], x1); atomicAdd(&cs[m2*3+2], 1.f);
  __syncthreads();
  if (tid < 192) atomicAdd(&csum[b * 192 + tid], cs[tid]);
  if (tid < 64) blkcnt[blockIdx.x * 64 + tid] = (int)cs[tid*3 + 2];
}

// ---------------- K2: means + prefix + counting-sort scatter ------------------------
__global__ __launch_bounds__(256) void k_mid(
    const float* __restrict__ csum, const int* __restrict__ blkcnt,
    const int* __restrict__ idx,
    float* __restrict__ noderot, int* __restrict__ rowflag,
    int* __restrict__ sorted) {
  __shared__ float cls[192];
  __shared__ int offs[64];
  __shared__ int lbase[64];
  __shared__ int lc[64];
  int tid = threadIdx.x;
  int blk = blockIdx.x;           // b*16 + chunk
  int b = blk >> 4, chunk = blk & 15;
  if (tid < 192) cls[tid] = csum[b * 192 + tid];
  __syncthreads();
  if (tid < 64) {
    int m = tid;
    float s0 = cls[m*3], s1 = cls[m*3+1], c = cls[m*3+2];
    float mx = s0 / (c + 1e-5f), my = s1 / (c + 1e-5f);
    rowflag[b*64 + m] = (c > 0.f) ? 1 : 0;
    for (int r = 0; r < 4; ++r) {
      float th = 1.5707964f * (float)r;
      float cr = cosf(th), sr = sinf(th);
      noderot[((b*4+r)*2+0)*64 + m] = cr*mx - sr*my;
      noderot[((b*4+r)*2+1)*64 + m] = sr*mx + cr*my;
    }
    lc[m] = 0;
  }
  if (tid == 0) {
    int acc = 0;
    for (int mm = 0; mm < 64; ++mm) { offs[mm] = acc; acc += (int)cls[mm*3+2]; }
  }
  __syncthreads();
  if (tid < 64) {
    int base = offs[tid];
    for (int c2 = 0; c2 < chunk; ++c2) base += blkcnt[(b*16 + c2)*64 + tid];
    lbase[tid] = base;
  }
  __syncthreads();
  int n = (chunk << 8) + tid;
#pragma unroll
  for (int kk = 0; kk < 3; ++kk) {
    int m = idx[((long)b*NN + n)*3 + kk];
    int pos = atomicAdd(&lc[m], 1);
    sorted[b*KNN + lbase[m] + pos] = (m << 12) | n;
  }
}

// ---------------- K3: fused fp block, 512 thr / 128 cols per block -------------------
// grid (96, 16). LDS = 52 KB -> 3 blocks/CU. mcol in Cs[col*136 + 130] padding slot.
__global__ __launch_bounds__(512, 6) void k_fused(
    const void* __restrict__ x, const int* __restrict__ sorted,
    const int* __restrict__ idx, const float* __restrict__ noderot,
    const unsigned short* __restrict__ Wb2,
    unsigned int* __restrict__ pooled, float* __restrict__ feat0) {
  __shared__ unsigned short Cs[128 * 136];
  __shared__ unsigned short Hs[128 * 72];
  const unsigned short* fW1 = Wb2 + F_W1;
  const unsigned short* fW2 = Wb2 + F_W2;
  const unsigned short* fW3 = Wb2 + F_W3;
  const unsigned short* fb1 = Wb2 + F_B1;
  const unsigned short* fb2 = Wb2 + F_B2;
  const unsigned short* fb3 = Wb2 + F_B3;
  const unsigned short* fb0 = Wb2 + F_B0;
  const unsigned short* fW0 = Wb2 + F_W0;
  int isbf = detect_bf((const unsigned short*)x);
  int tid = threadIdx.x, lane = tid & 63, wv = tid >> 6;   // wv 0..7
  int quad = lane >> 4, lr = lane & 15;
  int br = blockIdx.y, b = br >> 2, r = br & 3;
  if (tid < 128) {
    int e = sorted[b * KNN + blockIdx.x * 128 + tid];
    int m = e >> 12, n = e & 4095;
    int isz = (n == 0 && m == idx[(long)b * NN * 3]) ? 256 : 0;
    Cs[tid * 136 + 130] = (unsigned short)(m | isz);
    float x0 = ldf(x, b*8192 + n, isbf), x1 = ldf(x, b*8192 + 4096 + n, isbf);
    float th = 1.5707964f * (float)r;
    float cr = cosf(th), sr = sinf(th);
    float xd0 = (cr*x0 - sr*x1) - noderot[(br*2 + 0)*64 + m];
    float xd1 = (sr*x0 + cr*x1) - noderot[(br*2 + 1)*64 + m];
    *(unsigned int*)&Cs[tid * 136] = f2bf2(xd0, xd1);
  }
  __syncthreads();
  // ----- layer0 (2 -> 64), VALU -----
  {
    int col = tid & 127, og = (tid >> 7) << 4;
    unsigned int xu = *(unsigned int*)&Cs[col * 136];
    float fx0 = bf2f(xu & 0xffff), fx1 = bf2f(xu >> 16);
    union { unsigned int u[8]; bf16x8 v[2]; } o8;
#pragma unroll
    for (int j = 0; j < 16; j += 2) {
      int o = og + j;
      unsigned int wu0 = *(const unsigned int*)&fW0[o*2];
      unsigned int wu1 = *(const unsigned int*)&fW0[o*2 + 2];
      float h0 = bf2f(fb0[o])   + bf2f(wu0 & 0xffff)*fx0 + bf2f(wu0 >> 16)*fx1;
      float h1 = bf2f(fb0[o+1]) + bf2f(wu1 & 0xffff)*fx0 + bf2f(wu1 >> 16)*fx1;
      o8.u[j >> 1] = f2bf2(fmaxf(h0, 0.f), fmaxf(h1, 0.f));
    }
    *(bf16x8*)&Hs[col*72 + og]     = o8.v[0];
    *(bf16x8*)&Hs[col*72 + og + 8] = o8.v[1];
  }
  __syncthreads();
  // ----- layer1 (64 -> 64) -----
  {
    int o0 = (wv & 3) * 16, cb = (wv >> 2) * 64;
    f32x4 acc[4];
    float bb4[4];
#pragma unroll
    for (int rr = 0; rr < 4; ++rr) bb4[rr] = bf2f(fb1[o0 + quad*4 + rr]);
#pragma unroll
    for (int nt = 0; nt < 4; ++nt) acc[nt] = (f32x4){bb4[0], bb4[1], bb4[2], bb4[3]};
#pragma unroll
    for (int ks = 0; ks < 64; ks += 32) {
      bf16x8 a = *(const bf16x8*)(fW1 + (o0 + lr)*64 + ks + quad*8);
#pragma unroll
      for (int nt = 0; nt < 4; ++nt) {
        bf16x8 bf = *(bf16x8*)&Hs[(cb + nt*16 + lr)*72 + ks + quad*8];
        acc[nt] = __builtin_amdgcn_mfma_f32_16x16x32_bf16(a, bf, acc[nt], 0, 0, 0);
      }
    }
    __syncthreads();
#pragma unroll
    for (int nt = 0; nt < 4; ++nt) {
      int col = cb + nt*16 + lr;
      unsigned long long pk =
        (unsigned long long)f2bf2(fmaxf(acc[nt][0],0.f), fmaxf(acc[nt][1],0.f)) |
        ((unsigned long long)f2bf2(fmaxf(acc[nt][2],0.f), fmaxf(acc[nt][3],0.f)) << 32);
      *(unsigned long long*)&Hs[col*72 + o0 + quad*4] = pk;
    }
  }
  __syncthreads();
  // ----- layer2 (64 -> 128) -----
  {
    int o0 = wv * 16;
    f32x4 acc[8];
    float bb4[4];
#pragma unroll
    for (int rr = 0; rr < 4; ++rr) bb4[rr] = bf2f(fb2[o0 + quad*4 + rr]);
#pragma unroll
    for (int nt = 0; nt < 8; ++nt) acc[nt] = (f32x4){bb4[0], bb4[1], bb4[2], bb4[3]};
#pragma unroll
    for (int ks = 0; ks < 64; ks += 32) {
      bf16x8 a = *(const bf16x8*)(fW2 + (o0 + lr)*64 + ks + quad*8);
#pragma unroll
      for (int nt = 0; nt < 8; ++nt) {
        bf16x8 bf = *(bf16x8*)&Hs[(nt*16 + lr)*72 + ks + quad*8];
        acc[nt] = __builtin_amdgcn_mfma_f32_16x16x32_bf16(a, bf, acc[nt], 0, 0, 0);
      }
    }
#pragma unroll
    for (int nt = 0; nt < 8; ++nt) {
      int col = nt*16 + lr;
      int o = o0 + quad*4;
      *(unsigned int*)&Cs[col*136 + 2 + o] = f2bf2(fmaxf(acc[nt][0],0.f), fmaxf(acc[nt][1],0.f));
      *(unsigned int*)&Cs[col*136 + 4 + o] = f2bf2(fmaxf(acc[nt][2],0.f), fmaxf(acc[nt][3],0.f));
    }
  }
  __syncthreads();
  // ----- layer3 (130 -> 128) -----
  f32x4 acc3[8];
  {
    int o0 = wv * 16;
    float bb4[4];
#pragma unroll
    for (int rr = 0; rr < 4; ++rr) bb4[rr] = bf2f(fb3[o0 + quad*4 + rr]);
#pragma unroll
    for (int nt = 0; nt < 8; ++nt) acc3[nt] = (f32x4){bb4[0], bb4[1], bb4[2], bb4[3]};
#pragma unroll
    for (int ks = 0; ks < 128; ks += 32) {
      union { bf16x8 v; unsigned int u[4]; } au;
      const unsigned int* ap = (const unsigned int*)(fW3 + (long)(o0 + lr)*130 + ks + quad*8);
      au.u[0] = ap[0]; au.u[1] = ap[1]; au.u[2] = ap[2]; au.u[3] = ap[3];
#pragma unroll
      for (int nt = 0; nt < 8; ++nt) {
        bf16x8 bf = *(bf16x8*)&Cs[(nt*16 + lr)*136 + ks + quad*8];
        acc3[nt] = __builtin_amdgcn_mfma_f32_16x16x32_bf16(au.v, bf, acc3[nt], 0, 0, 0);
      }
    }
    float bu0[8], bu1[8];
#pragma unroll
    for (int nt = 0; nt < 8; ++nt) {
      unsigned int bu = *(unsigned int*)&Cs[(nt*16 + lr)*136 + 128];
      bu0[nt] = bf2f(bu & 0xffff); bu1[nt] = bf2f(bu >> 16);
    }
#pragma unroll
    for (int rr = 0; rr < 4; ++rr) {
      int o = o0 + quad*4 + rr;
      unsigned int wu = *(const unsigned int*)(fW3 + (long)o*130 + 128);
      float w0 = bf2f(wu & 0xffff), w1 = bf2f(wu >> 16);
#pragma unroll
      for (int nt = 0; nt < 8; ++nt)
        acc3[nt][rr] += w0 * bu0[nt] + w1 * bu1[nt];
    }
  }
  __syncthreads();
  {
    int o0 = wv * 16;
#pragma unroll
    for (int nt = 0; nt < 8; ++nt) {
      int col = nt*16 + lr;
      unsigned long long pk =
        (unsigned long long)f2bf2(fmaxf(acc3[nt][0],0.f), fmaxf(acc3[nt][1],0.f)) |
        ((unsigned long long)f2bf2(fmaxf(acc3[nt][2],0.f), fmaxf(acc3[nt][3],0.f)) << 32);
      *(unsigned long long*)&Cs[col*136 + o0 + quad*4] = pk;
    }
  }
  __syncthreads();
  // ----- run-scan segment max -----
  {
    int o = tid & 127, h = tid >> 7;
    int c0 = h * 32;
    float fv[32];
    int mcl[32];
#pragma unroll
    for (int j = 0; j < 32; ++j) {
      fv[j] = bf2f(Cs[(c0 + j)*136 + o]);
      mcl[j] = Cs[(c0 + j)*136 + 130];
    }
    int curm = mcl[0] & 255;
    float v = 0.f;
#pragma unroll
    for (int j = 0; j < 32; ++j) {
      int mm = mcl[j] & 255;
      if (mm != curm) {
        atomicMax(&pooled[(((long)br*64 + curm) << 7) + o], __float_as_uint(v));
        curm = mm; v = 0.f;
      }
      v = fmaxf(v, fv[j]);
      if (mcl[j] & 256) feat0[br*128 + o] = fv[j];
    }
    atomicMax(&pooled[(((long)br*64 + curm) << 7) + o], __float_as_uint(v));
  }
}

// ---------------- K4: finalize -> AG[1024][648] cols 0..129 -------------------------
__global__ __launch_bounds__(256) void k_fin(
    const unsigned int* __restrict__ pooled, const float* __restrict__ feat0,
    const int* __restrict__ rowflag, const float* __restrict__ noderot,
    unsigned short* __restrict__ AG) {
  int t = blockIdx.x * 256 + threadIdx.x;
  int col = t >> 7, o = t & 127;
  int br = col >> 6, m = col & 63, b = br >> 2;
  float v = __uint_as_float(pooled[((long)col << 7) + o]);
  if (!rowflag[b*64 + m]) v = feat0[br*128 + o];
  AG[(long)col*648 + 2 + o] = f2bf(v);
  if (o < 2) AG[(long)col*648 + o] = f2bf(noderot[(br*2 + o)*64 + m]);
}

// ---------------- gp GEMM v3: packed-A (coalesced) + LDS B-staging ------------------
// grid (64 col-tiles, R/64 row-blocks). wave = 16 rows x 16 cols. K padded to KP.
template<int KP, int KREAD, int R, int BSTR, int OSTR, int OOFF, int EPI, int TOTB>
__global__ __launch_bounds__(256) void k_gemm3(
    const unsigned short* __restrict__ A, const unsigned short* __restrict__ Bi,
    const unsigned short* __restrict__ Bb, unsigned short* __restrict__ Out,
    unsigned int* __restrict__ outmax, unsigned int* __restrict__ counter,
    const void* __restrict__ x, void* __restrict__ out) {
  constexpr int KPL = KP + 8;               // LDS stride: 2-way bank alias only
  __shared__ unsigned short Bs[16 * KPL];
  __shared__ int done_s;
  int tid = threadIdx.x;
  int lane = tid & 63, wv = tid >> 6;
  int quad = lane >> 4, lr = lane & 15;
  int o0 = blockIdx.y * 64 + wv * 16;
  int p0 = blockIdx.x * 16;
  // ---- stage B tile (coalesced dwords, zero-pad K tail) ----
  for (int i = tid; i < 16 * (KP/2); i += 256) {
    int row = i / (KP/2), kd = i - row * (KP/2);
    int k = kd * 2;
    unsigned int v = 0u;
    if (k < KREAD) v = *(const unsigned int*)(Bb + (long)(p0 + row) * BSTR + k);
    *(unsigned int*)&Bs[row * KPL + k] = v;
  }
  f32x4 acc;
  {
    int ob = o0 + quad*4;
    acc = (f32x4){bf2f(Bi[ob]), bf2f(Bi[ob+1]), bf2f(Bi[ob+2]), bf2f(Bi[ob+3])};
  }
  __syncthreads();
#pragma unroll
  for (int ks = 0; ks < KP; ks += 32) {
    bf16x8 a = *(const bf16x8*)(A + ((ks >> 3) + quad) * (R * 8) + (o0 + lr) * 8);
    bf16x8 b = *(const bf16x8*)&Bs[lr * KPL + ks + quad * 8];
    acc = __builtin_amdgcn_mfma_f32_16x16x32_bf16(a, b, acc, 0, 0, 0);
  }
  if constexpr (EPI == 0) {
    unsigned short* op = Out + (long)(p0 + lr) * OSTR + OOFF + o0 + quad*4;
    if constexpr (((OOFF * 2) % 8) == 0) {
      unsigned long long pk =
        (unsigned long long)f2bf2(fmaxf(acc[0],0.f), fmaxf(acc[1],0.f)) |
        ((unsigned long long)f2bf2(fmaxf(acc[2],0.f), fmaxf(acc[3],0.f)) << 32);
      *(unsigned long long*)op = pk;
    } else {
      *(unsigned int*)op       = f2bf2(fmaxf(acc[0],0.f), fmaxf(acc[1],0.f));
      *(unsigned int*)(op + 2) = f2bf2(fmaxf(acc[2],0.f), fmaxf(acc[3],0.f));
    }
  } else {  // EPI == 2: 16 cols in one br -> b = blockIdx.x>>4; then counter-out
    int b = blockIdx.x >> 4;
#pragma unroll
    for (int rr = 0; rr < 4; ++rr) {
      float v = fmaxf(acc[rr], 0.f);
      v = fmaxf(v, __shfl_xor(v, 1, 64));
      v = fmaxf(v, __shfl_xor(v, 2, 64));
      v = fmaxf(v, __shfl_xor(v, 4, 64));
      v = fmaxf(v, __shfl_xor(v, 8, 64));
      if (lr == 0) atomicMax(&outmax[b * FF + o0 + quad*4 + rr], __float_as_uint(v));
    }
    __threadfence();
    __syncthreads();
    if (tid == 0) done_s = (int)atomicAdd(counter, 1u);
    __syncthreads();
    if (done_s == TOTB - 1) {
      int isbf = detect_bf((const unsigned short*)x);
      for (int t = tid; t < 2048; t += 256) {
        float v = __uint_as_float(atomicMax(&outmax[t], 0u));
        if (isbf) ((unsigned short*)out)[t] = f2bf(v);
        else      ((float*)out)[t] = v;
      }
    }
  }
}

// ---------------- host ----------------
extern "C" void kernel_launch(void* const* d_in, const int* in_sizes, int n_in,
                              void* d_out, int out_size, void* d_ws, size_t ws_size,
                              hipStream_t stream) {
  const void* x    = d_in[0];
  const void* node = d_in[2];

  char* ws = (char*)d_ws;
  float*          csum    = (float*)(ws + 0);              //   3072
  unsigned int*   outmax  = (unsigned int*)(ws + 3072);    //   8192
  unsigned int*   counter = (unsigned int*)(ws + 11264);   //    256
  // ---- end of memset region (11520 B) ----
  unsigned int*   pooled  = (unsigned int*)(ws + 11520);   // 524288 (zeroed by k_pre)
  int*            idx     = (int*)(ws + 535808);           // 196608
  int*            blkcnt  = (int*)(ws + 732416);           //  16384
  float*          noderot = (float*)(ws + 748800);         //   8192
  int*            rowflag = (int*)(ws + 756992);           //   1024
  int*            sorted  = (int*)(ws + 758016);           // 196608
  float*          feat0   = (float*)(ws + 954624);         //   8192
  unsigned short* Wp      = (unsigned short*)(ws + 962816);   // 1163264 -> 2126080
  unsigned short* Wb2     = (unsigned short*)(ws + 2126080);  //   61952 -> 2188032
  unsigned short* AG      = (unsigned short*)(ws + 2188032);  // 1327104 -> 3515136
  unsigned short* Hg1     = (unsigned short*)(ws + 3515136);  //  524288 -> 4039424
  unsigned short* Hg2     = (unsigned short*)(ws + 4039424);  //  524288 -> 4563712

  hipMemsetAsync(ws, 0, 11520, stream);

  SrcPtrs sp;
  sp.p[0]  = d_in[6];   // fpW1
  sp.p[1]  = d_in[8];   // fpW2
  sp.p[2]  = d_in[10];  // fpW3
  sp.p[3]  = d_in[12];  // gpW0
  sp.p[4]  = d_in[14];  // gpW1
  sp.p[5]  = d_in[16];  // gpW2
  sp.p[6]  = d_in[18];  // gpW3
  sp.p[7]  = d_in[7];   // fpb1
  sp.p[8]  = d_in[9];   // fpb2
  sp.p[9]  = d_in[11];  // fpb3
  sp.p[10] = d_in[13];  // gpb0
  sp.p[11] = d_in[15];  // gpb1
  sp.p[12] = d_in[17];  // gpb2
  sp.p[13] = d_in[19];  // gpb3
  sp.p[14] = d_in[5];   // fpb0
  sp.p[15] = d_in[4];   // fpW0

  // grid: 64 assign + 61 Wb2-cvt (blocks 64..124) + 1136 packed-cvt (125..1260)
  k_pre<<<1261, 256, 0, stream>>>(sp, x, node, idx, csum, blkcnt, Wb2, Wp,
                                  (unsigned long long*)pooled);
  k_mid<<<64, 256, 0, stream>>>(csum, blkcnt, idx, noderot, rowflag, sorted);
  k_fused<<<dim3(96, 16), 512, 0, stream>>>(x, sorted, idx, noderot, Wb2, pooled, feat0);
  k_fin<<<512, 256, 0, stream>>>(pooled, feat0, rowflag, noderot, AG);

  // gp layers: packed A + LDS-staged B
  k_gemm3<160, 130, 256, 648, 256, 0, 0, 0>
      <<<dim3(64, 4), 256, 0, stream>>>(Wp + P_W0, Wb2 + G_B0, AG, Hg1,
                                        nullptr, nullptr, x, nullptr);
  k_gemm3<256, 256, 256, 256, 256, 0, 0, 0>
      <<<dim3(64, 4), 256, 0, stream>>>(Wp + P_W1, Wb2 + G_B1, Hg1, Hg2,
                                        nullptr, nullptr, x, nullptr);
  k_gemm3<256, 256, 512, 256, 648, 130, 0, 0>
      <<<dim3(64, 8), 256, 0, stream>>>(Wp + P_W2, Wb2 + G_B2, Hg2, AG,
                                        nullptr, nullptr, x, nullptr);
  k_gemm3<672, 642, 512, 648, 0, 0, 2, 512>
      <<<dim3(64, 8), 256, 0, stream>>>(Wp + P_W3, Wb2 + G_B3, AG, nullptr,
                                        outmax, counter, x, d_out);
}